// Round 15
// baseline (146.916 us; speedup 1.0000x reference)
//
#include <hip/hip_runtime.h>
#include <stdint.h>
#include <stddef.h>

typedef __attribute__((ext_vector_type(4))) float  f32x4;
typedef __attribute__((ext_vector_type(8))) short  short8;
typedef __attribute__((ext_vector_type(4))) short  short4v;
typedef __attribute__((ext_vector_type(2))) unsigned int uint2v;

__device__ __forceinline__ unsigned short f2bfbits(float f) {
  unsigned int u = __builtin_bit_cast(unsigned int, f);
  u += 0x7FFFu + ((u >> 16) & 1u);   // RNE
  return (unsigned short)(u >> 16);
}

__device__ __forceinline__ f32x4 mfma16(short8 a, short8 b, f32x4 c) {
  return __builtin_amdgcn_mfma_f32_16x16x32_bf16(a, b, c, 0, 0, 0);
}

__device__ __forceinline__ unsigned int cvtpk(float a, float b) {
  unsigned int r;
  asm volatile("v_cvt_pk_bf16_f32 %0, %1, %2" : "=v"(r) : "v"(a), "v"(b));
  return r;
}

__device__ __forceinline__ void gload16(const void* g, void* l) {
  __builtin_amdgcn_global_load_lds(
      (const __attribute__((address_space(1))) void*)g,
      (__attribute__((address_space(3))) void*)l, 16, 0, 0);
}

// ---------------------------------------------------------------- fused prep
// Blocks [0,7168): f32->bf16 of {x,y,Wq,Wkv,Wo}.
// Blocks 7168+b: per-batch mask scan -> invperm (slot -> original row;
// bijection) + compacted bias maddC[b][slot] = -10 (slot<nvalid) / -1e30.
__device__ __forceinline__ void cvt_block(const float* __restrict__ in,
                                          unsigned short* __restrict__ out,
                                          int blk, int t) {
  size_t i = (size_t)blk * 256 + t;    // in units of 8 elements
  f32x4 a = *(const f32x4*)(in + i * 8);
  f32x4 b = *(const f32x4*)(in + i * 8 + 4);
  short8 o;
  o[0] = (short)f2bfbits(a[0]); o[1] = (short)f2bfbits(a[1]);
  o[2] = (short)f2bfbits(a[2]); o[3] = (short)f2bfbits(a[3]);
  o[4] = (short)f2bfbits(b[0]); o[5] = (short)f2bfbits(b[1]);
  o[6] = (short)f2bfbits(b[2]); o[7] = (short)f2bfbits(b[3]);
  *(short8*)(out + i * 8) = o;
}

__global__ __launch_bounds__(256) void fused_prep(
    const float* __restrict__ x, unsigned short* __restrict__ xb,
    const float* __restrict__ y, unsigned short* __restrict__ yb,
    const float* __restrict__ Wq, unsigned short* __restrict__ Wqb,
    const float* __restrict__ Wkv, unsigned short* __restrict__ Wkvb,
    const float* __restrict__ Wo, unsigned short* __restrict__ Wob,
    const unsigned char* __restrict__ mraw, float* __restrict__ maddC,
    int* __restrict__ invperm, int* __restrict__ nvalid) {
  const int bid = blockIdx.x, t = threadIdx.x;
  if (bid < 2048)       { cvt_block(x,   xb,   bid,        t); return; }
  else if (bid < 5120)  { cvt_block(y,   yb,   bid - 2048, t); return; }
  else if (bid < 5632)  { cvt_block(Wq,  Wqb,  bid - 5120, t); return; }
  else if (bid < 6656)  { cvt_block(Wkv, Wkvb, bid - 5632, t); return; }
  else if (bid < 7168)  { cvt_block(Wo,  Wob,  bid - 6656, t); return; }

  // ---- mask scan block (one per batch) ----
  const int batch = bid - 7168;
  __shared__ int s_na, s_gt, s_m84;
  if (t == 0) { s_na = 0; s_gt = 0; s_m84 = 0; }
  __syncthreads();
  int na = 0, gt = 0, m84 = 0;
  for (int i = t; i < 4096; i += 256) {
    unsigned char v = mraw[i];
    if (v) {
      if (i & 3) na++;
      if ((i & 7) == 4) m84++;
      if (v > 1) gt++;
    }
  }
  atomicAdd(&s_na, na); atomicAdd(&s_gt, gt); atomicAdd(&s_m84, m84);
  __syncthreads();
  int layout;                        // 0=bool8 1=int32 2=float32 3=int64
  if (s_na == 0) layout = s_m84 ? 1 : 3;
  else           layout = s_gt ? 2 : 0;

  const int base = batch * 3072;
  int myv[12];
  int cnt = 0;
#pragma unroll
  for (int k = 0; k < 12; k++) {
    int j = t * 12 + k;
    int gj = base + j;
    bool mv;
    if (layout == 0)      mv = mraw[gj] != 0;
    else if (layout == 1) mv = ((const int*)mraw)[gj] != 0;
    else if (layout == 2) mv = ((const float*)mraw)[gj] > 0.5f;
    else                  mv = ((const long long*)mraw)[gj] != 0;
    myv[k] = mv ? 1 : 0;
    cnt += myv[k];
  }
  const int lane = t & 63, wv = t >> 6;
  int inc = cnt;
#pragma unroll
  for (int d = 1; d < 64; d <<= 1) {
    int n = __shfl_up(inc, d);
    if (lane >= d) inc += n;
  }
  __shared__ int wsum[4];
  if (lane == 63) wsum[wv] = inc;
  __syncthreads();
  int woff = 0;
#pragma unroll
  for (int i2 = 0; i2 < 4; i2++) if (i2 < wv) woff += wsum[i2];
  const int total = wsum[0] + wsum[1] + wsum[2] + wsum[3];
  int vp = woff + inc - cnt;         // #valid before my first element
  if (t == 0) nvalid[batch] = total;
#pragma unroll
  for (int k = 0; k < 12; k++) {
    int j = t * 12 + k;
    int slot = myv[k] ? vp : (total + (j - vp));
    invperm[base + slot] = j;
    vp += myv[k];
  }
  for (int jj = t; jj < 3072; jj += 256)
    maddC[base + jj] = (jj < total) ? -10.0f : -1e30f;
}

// ---------------------------------------------------------------- qkv GEMM
// Merged q + kv projection, flat 1024-block launch, XCD-balanced swizzle.
// T3 minimum-2-phase: double-buffered LDS (64 KB — free, since VGPR 180/wave
// already caps at 2 blocks/CU), stage(t+1) ISSUED BEFORE compute(t), single
// barrier per K-tile (its vmcnt(0) drain lands the prefetch).
__global__ __launch_bounds__(256) void gemm_qkv(
    const unsigned short* __restrict__ xb, const unsigned short* __restrict__ Wqb,
    const float* __restrict__ bq, const float* __restrict__ qnw,
    const float* __restrict__ qnb, unsigned short* __restrict__ qln,
    const unsigned short* __restrict__ yb, const unsigned short* __restrict__ Wkvb,
    const float* __restrict__ bkv, const float* __restrict__ knw,
    const float* __restrict__ knb, unsigned short* __restrict__ kln,
    unsigned short* __restrict__ vrow) {
  __shared__ unsigned short As[2 * 128 * 64];
  __shared__ unsigned short Bs[2 * 128 * 64];
  const int t = threadIdx.x, l = t & 63, w = t >> 6;
  const int lo = l & 15, hi = l >> 4;
  const int wr = w >> 1, wc = w & 1;
  const int flat = blockIdx.x;
  int vb;
  if (flat < 256) vb = (flat & 7) * 32 + (flat >> 3);
  else { int f2 = flat - 256; vb = 256 + (f2 & 7) * 96 + (f2 >> 3); }
  const int isq = vb < 256;
  const int bn = isq ? (vb & 7) : ((vb - 256) & 15);
  const int bm = isq ? (vb >> 3) : ((vb - 256) >> 4);
  const unsigned short* A = isq ? xb : yb;
  const unsigned short* B = isq ? Wqb : Wkvb;
  const float* bias = isq ? bq : bkv;
  const float* lnw = isq ? qnw : knw;
  const float* lnb = isq ? qnb : knb;
  unsigned short* bfout = isq ? qln : kln;
  const float lnscale = isq ? 0.125f * 1.44269504f : 1.0f;
  const int rpb = isq ? 2048 : 3072;
  const int K = 1024;

  const int sr = l >> 3;
  const int sc = ((l & 7) ^ sr) << 3;
  const unsigned short* Ab = A + (size_t)bm * 128 * K + (size_t)sr * K + sc;
  const unsigned short* Bb = B + (size_t)bn * 128 * K + (size_t)sr * K + sc;

  f32x4 acc[4][4] = {};

  // prologue: stage tile 0 into buf 0
#pragma unroll
  for (int p = 0; p < 4; ++p) {
    int c = w * 4 + p;
    gload16(Ab + (size_t)c * 8 * K, &As[c * 512]);
    gload16(Bb + (size_t)c * 8 * K, &Bs[c * 512]);
  }
  __syncthreads();   // drains vmcnt(0): tile 0 ready

  for (int kt = 0; kt < K; kt += 64) {
    const int cur = (kt >> 6) & 1;
    const int nxt = cur ^ 1;
    const int ktn = (kt + 64 < K) ? kt + 64 : 0;   // wrap re-stage harmless
    // issue next-tile stage FIRST (hides under this tile's compute)
#pragma unroll
    for (int p = 0; p < 4; ++p) {
      int c = w * 4 + p;
      gload16(Ab + (size_t)c * 8 * K + ktn, &As[nxt * 8192 + c * 512]);
      gload16(Bb + (size_t)c * 8 * K + ktn, &Bs[nxt * 8192 + c * 512]);
    }
#pragma unroll
    for (int kk = 0; kk < 2; ++kk) {
      short8 af[4], bf[4];
#pragma unroll
      for (int i = 0; i < 4; ++i) {
        int slot = (((kk * 4 + hi) ^ (lo & 7)) << 3);
        af[i] = *(const short8*)&As[cur * 8192 + (wr * 64 + i * 16 + lo) * 64 + slot];
        bf[i] = *(const short8*)&Bs[cur * 8192 + (wc * 64 + i * 16 + lo) * 64 + slot];
      }
#pragma unroll
      for (int i = 0; i < 4; ++i)
#pragma unroll
        for (int j = 0; j < 4; ++j)
          acc[i][j] = mfma16(af[i], bf[j], acc[i][j]);
    }
    __syncthreads();  // vmcnt(0)+lgkm drain: prefetch landed, reads done
  }

  float bv[4];
#pragma unroll
  for (int j = 0; j < 4; ++j) bv[j] = bias[bn * 128 + wc * 64 + j * 16 + lo];
#pragma unroll
  for (int i = 0; i < 4; ++i)
#pragma unroll
    for (int j = 0; j < 4; ++j)
#pragma unroll
      for (int r = 0; r < 4; ++r) acc[i][j][r] += bv[j];

  if (!isq && bn >= 8) {
    // V half: coalesced bf16 store, original row order (j = kv row)
#pragma unroll
    for (int j = 0; j < 4; ++j) {
      int col = bn * 128 + wc * 64 + j * 16 + lo;
      int vcol = col - 1024;
#pragma unroll
      for (int i = 0; i < 4; ++i) {
        int row = bm * 128 + wr * 64 + i * 16 + hi * 4;
#pragma unroll
        for (int r = 0; r < 4; ++r)
          vrow[(size_t)(row + r) * 1024 + vcol] = f2bfbits(acc[i][j][r]);
      }
    }
  } else {
    // fused per-head LayerNorm -> bf16 head-major [b*16+h][rpb][64]
    float gwv[4], gbv[4];
#pragma unroll
    for (int j = 0; j < 4; ++j) {
      gwv[j] = lnw[j * 16 + lo];
      gbv[j] = lnb[j * 16 + lo];
    }
    const int hcol = (bn * 128 + wc * 64) >> 6;
#pragma unroll
    for (int i = 0; i < 4; ++i) {
#pragma unroll
      for (int r = 0; r < 4; ++r) {
        float s1 = (acc[i][0][r] + acc[i][1][r]) + (acc[i][2][r] + acc[i][3][r]);
        float s2 = (acc[i][0][r] * acc[i][0][r] + acc[i][1][r] * acc[i][1][r]) +
                   (acc[i][2][r] * acc[i][2][r] + acc[i][3][r] * acc[i][3][r]);
#pragma unroll
        for (int m = 1; m < 16; m <<= 1) {
          s1 += __shfl_xor(s1, m);
          s2 += __shfl_xor(s2, m);
        }
        float mu = s1 * 0.015625f;
        float var = fmaxf(s2 * 0.015625f - mu * mu, 0.0f);
        float rq = rsqrtf(var + 1e-6f);
        int row = bm * 128 + wr * 64 + i * 16 + hi * 4 + r;
        int bb = row >= rpb;
        int rr = row - bb * rpb;
        size_t base = ((size_t)(bb * 16 + hcol) * rpb + rr) * 64;
#pragma unroll
        for (int j = 0; j < 4; ++j)
          bfout[base + j * 16 + lo] =
              f2bfbits(((acc[i][j][r] - mu) * rq * gwv[j] + gbv[j]) * lnscale);
      }
    }
  }
}

// ---------------------------------------------------------------- V gather+T
// vt[(b*16+h)*64 + d][slot] = vrow[b*3072 + invperm[slot]][h*64 + d].
__global__ __launch_bounds__(256) void v_tr(
    const unsigned short* __restrict__ vrow, const int* __restrict__ invperm,
    unsigned short* __restrict__ vt) {
  __shared__ unsigned short tile[64][65];
  const int jt = blockIdx.x, h = blockIdx.y;   // jt 0..95 (48 per batch)
  const int b = jt / 48, j0 = (jt % 48) * 64;
  const int t = threadIdx.x;
  const int r = t >> 2, c0 = (t & 3) << 4;
  const int sj = invperm[b * 3072 + j0 + r];
  const unsigned short* src = vrow + ((size_t)b * 3072 + sj) * 1024 + h * 64 + c0;
  *(short8*)&tile[r][c0]     = *(const short8*)src;
  *(short8*)&tile[r][c0 + 8] = *(const short8*)(src + 8);
  __syncthreads();
  const int d = t >> 2, jc = (t & 3) << 4;
  unsigned short* dst = vt + ((size_t)((b * 16 + h) * 64 + d)) * 3072 + j0 + jc;
  short8 o0, o1;
#pragma unroll
  for (int i = 0; i < 8; i++) o0[i] = tile[jc + i][d];
#pragma unroll
  for (int i = 0; i < 8; i++) o1[i] = tile[jc + 8 + i][d];
  *(short8*)dst = o0;
  *(short8*)(dst + 8) = o1;
}

// ---------------------------------------------------------------- out GEMM
// out = ctx@Wo^T + bo. 512 threads, 8 waves (4M x 2N); T3 2-phase dbuf.
__global__ __launch_bounds__(512) void gemm_out(
    const unsigned short* __restrict__ A, const unsigned short* __restrict__ B,
    const float* __restrict__ bias, float* __restrict__ C, int N, int K) {
  __shared__ unsigned short As[2 * 128 * 64];
  __shared__ unsigned short Bs[2 * 128 * 64];
  const int t = threadIdx.x, l = t & 63, w = t >> 6;
  const int lo = l & 15, hi = l >> 4;
  const int wr = w >> 1, wc = w & 1;          // 4M x 2N
  const int bn = blockIdx.x, bm = blockIdx.y;

  const int sr = l >> 3;
  const int sc = ((l & 7) ^ sr) << 3;
  const unsigned short* Ab = A + (size_t)bm * 128 * K + (size_t)sr * K + sc;
  const unsigned short* Bb = B + (size_t)bn * 128 * K + (size_t)sr * K + sc;

  f32x4 acc[2][4] = {};

  // prologue: stage tile 0
#pragma unroll
  for (int p = 0; p < 2; ++p) {
    int c = p * 8 + w;
    gload16(Ab + (size_t)c * 8 * K, &As[c * 512]);
    gload16(Bb + (size_t)c * 8 * K, &Bs[c * 512]);
  }
  __syncthreads();

  for (int kt = 0; kt < K; kt += 64) {
    const int cur = (kt >> 6) & 1;
    const int nxt = cur ^ 1;
    const int ktn = (kt + 64 < K) ? kt + 64 : 0;
#pragma unroll
    for (int p = 0; p < 2; ++p) {
      int c = p * 8 + w;
      gload16(Ab + (size_t)c * 8 * K + ktn, &As[nxt * 8192 + c * 512]);
      gload16(Bb + (size_t)c * 8 * K + ktn, &Bs[nxt * 8192 + c * 512]);
    }
#pragma unroll
    for (int kk = 0; kk < 2; ++kk) {
      short8 af[2], bf[4];
#pragma unroll
      for (int i = 0; i < 2; ++i) {
        int slot = (((kk * 4 + hi) ^ (lo & 7)) << 3);
        af[i] = *(const short8*)&As[cur * 8192 + (wr * 32 + i * 16 + lo) * 64 + slot];
      }
#pragma unroll
      for (int j = 0; j < 4; ++j) {
        int slot = (((kk * 4 + hi) ^ (lo & 7)) << 3);
        bf[j] = *(const short8*)&Bs[cur * 8192 + (wc * 64 + j * 16 + lo) * 64 + slot];
      }
#pragma unroll
      for (int i = 0; i < 2; ++i)
#pragma unroll
        for (int j = 0; j < 4; ++j)
          acc[i][j] = mfma16(af[i], bf[j], acc[i][j]);
    }
    __syncthreads();
  }

#pragma unroll
  for (int j = 0; j < 4; ++j) {
    int col = bn * 128 + wc * 64 + j * 16 + lo;
    float bv = bias[col];
#pragma unroll
    for (int i = 0; i < 2; ++i) {
      int row = bm * 128 + wr * 32 + i * 16 + hi * 4;
#pragma unroll
      for (int r = 0; r < 4; ++r)
        C[(size_t)(row + r) * N + col] = acc[i][j][r] + bv;
    }
  }
}

// ---------------------------------------------------------------- attention
// REVERTED to the round-12 structure (proven): KVBLK=64, 40 KB LDS, T15
// 2-deep pipeline, KV compacted via invperm gather at K staging (per-lane
// global source, linear LDS dest), 128B-row XOR swizzle (conflict-clean).
// New this round: fully-valid tiles (kt+64 <= nvalid) use CONSTANT -10 as
// the QK C-init instead of a latency-exposed dependent mask load.
__global__ __launch_bounds__(256, 4) void attn_fwd(
    const unsigned short* __restrict__ Q, const unsigned short* __restrict__ KnU,
    const unsigned short* __restrict__ Vt, const float* __restrict__ maskAdd,
    const int* __restrict__ invperm, const int* __restrict__ nva,
    unsigned short* __restrict__ ctx) {
  int flat = blockIdx.y * 32 + blockIdx.x;
  int f = (flat & 7) * 128 + (flat >> 3);       // XCD i owns bh in [4i,4i+4)
  const int bh = f >> 5, qb = f & 31;
  const int b = bh >> 4, h = bh & 15;
  const int t = threadIdx.x, l = t & 63, w = t >> 6;
  const int lo = l & 15, hi = l >> 4;
  const int q0 = qb * 64 + w * 16;

  const int nv = nva[b];
  const int kend = (nv + 63) & ~63;             // >= 64 (mask[:,0]=True)

  __shared__ unsigned short lds[20480];         // 40 KB exactly
  unsigned short* Ks = lds;                     // [2][64][64]
  unsigned short* Vs = lds + 8192;              // [2][64][64]
  unsigned short* P  = lds + 16384 + w * 1024;  // [16][64] swizzled

  const unsigned short* Qh = Q + ((size_t)bh * 2048 + q0) * 64;
  const unsigned short* KbU = KnU + (size_t)bh * 3072 * 64;
  const unsigned short* Vb = Vt + (size_t)bh * 64 * 3072;
  const float* mb = maskAdd + b * 3072;
  const int ibase = b * 3072;

  const int srow = w * 8 + (l >> 3);            // in [0,32)
  const int swz8 = ((l & 7) ^ ((l >> 3) & 7)) << 3;
  const unsigned short* vS = Vb + (size_t)srow * 3072 + swz8;
  const int dstoff = w * 512;

  short8 qf[2];
#pragma unroll
  for (int g = 0; g < 2; g++)
    qf[g] = *(const short8*)(Qh + (size_t)lo * 64 + g * 32 + hi * 8);

  f32x4 O[4] = {};
  f32x4 lacc = {};
  const int myswz = (lo & 7) << 3;

  short8 paR[2] = {};
  short8 vfR[4][2] = {};

  // rows for tile 0
  int rs0 = invperm[ibase + srow];
  int rs1 = invperm[ibase + 32 + srow];
  gload16(KbU + (size_t)rs0 * 64 + swz8, Ks + dstoff);
  gload16(KbU + (size_t)rs1 * 64 + swz8, Ks + 2048 + dstoff);
  gload16(vS, Vs + dstoff);
  gload16(vS + 98304, Vs + 2048 + dstoff);
  {
    int kt1 = (64 < kend) ? 64 : 0;
    rs0 = invperm[ibase + kt1 + srow];
    rs1 = invperm[ibase + kt1 + 32 + srow];
  }
  __syncthreads();

  for (int kt = 0; kt < kend; kt += 64) {
    const int cur = (kt >> 6) & 1;
    const int nxt = cur ^ 1;
    const int ktn = (kt + 64 < kend) ? kt + 64 : 0;
    gload16(KbU + (size_t)rs0 * 64 + swz8, Ks + nxt * 4096 + dstoff);
    gload16(KbU + (size_t)rs1 * 64 + swz8, Ks + nxt * 4096 + 2048 + dstoff);
    gload16(vS + ktn, Vs + nxt * 4096 + dstoff);
    gload16(vS + ktn + 98304, Vs + nxt * 4096 + 2048 + dstoff);
    {
      int ktn2 = (kt + 128 < kend) ? kt + 128 : 0;
      rs0 = invperm[ibase + ktn2 + srow];
      rs1 = invperm[ibase + ktn2 + 32 + srow];
    }

    const unsigned short* Kc = Ks + cur * 4096;
    const unsigned short* Vc = Vs + cur * 4096;

    // QK^T(t) with mask bias as C-init; constant -10 for fully-valid tiles
    f32x4 s[4];
    if (kt + 64 <= nv) {
#pragma unroll
      for (int nf = 0; nf < 4; nf++)
        s[nf] = f32x4{-10.0f, -10.0f, -10.0f, -10.0f};
    } else {
#pragma unroll
      for (int nf = 0; nf < 4; nf++)
        s[nf] = *(const f32x4*)(mb + kt + nf * 16 + hi * 4);
    }
    __builtin_amdgcn_s_setprio(1);
#pragma unroll
    for (int nf = 0; nf < 4; nf++) {
      const int row = nf * 16 + lo;
      short8 k0 = *(const short8*)&Kc[row * 64 + ((hi * 8) ^ myswz)];
      short8 k1 = *(const short8*)&Kc[row * 64 + ((32 + hi * 8) ^ myswz)];
      s[nf] = mfma16(k0, qf[0], s[nf]);
      s[nf] = mfma16(k1, qf[1], s[nf]);
    }

    // PV(t-1): register-only MFMA cluster
#pragma unroll
    for (int df = 0; df < 4; df++)
#pragma unroll
      for (int ks = 0; ks < 2; ks++)
        O[df] = mfma16(paR[ks], vfR[df][ks], O[df]);
    __builtin_amdgcn_s_setprio(0);

    // P = exp2(S + bias)
#pragma unroll
    for (int nf = 0; nf < 4; nf++)
#pragma unroll
      for (int r = 0; r < 4; r++)
        s[nf][r] = __builtin_amdgcn_exp2f(s[nf][r]);
    lacc += (s[0] + s[1]) + (s[2] + s[3]);

    // P(t) -> LDS, preload pa(t)/vf(t) pipeline regs
#pragma unroll
    for (int nf = 0; nf < 4; nf++) {
      uint2v u;
      u.x = cvtpk(s[nf][0], s[nf][1]);
      u.y = cvtpk(s[nf][2], s[nf][3]);
      *(uint2v*)&P[lo * 64 + ((nf * 16 + hi * 4) ^ myswz)] = u;
    }
#pragma unroll
    for (int ks = 0; ks < 2; ks++)
      paR[ks] = *(const short8*)&P[lo * 64 + ((ks * 32 + hi * 8) ^ myswz)];
#pragma unroll
    for (int df = 0; df < 4; df++) {
      const int row = df * 16 + lo;
#pragma unroll
      for (int ks = 0; ks < 2; ks++)
        vfR[df][ks] = *(const short8*)&Vc[row * 64 + ((ks * 32 + hi * 8) ^ myswz)];
    }

    __syncthreads();   // drains vmcnt+lgkm: paR/vfR live; buffers safe
  }

  // epilogue: PV of the last tile
  __builtin_amdgcn_s_setprio(1);
#pragma unroll
  for (int df = 0; df < 4; df++)
#pragma unroll
    for (int ks = 0; ks < 2; ks++)
      O[df] = mfma16(paR[ks], vfR[df][ks], O[df]);
  __builtin_amdgcn_s_setprio(0);

  float lr = (lacc[0] + lacc[1]) + (lacc[2] + lacc[3]);
  lr += __shfl_xor(lr, 16);
  lr += __shfl_xor(lr, 32);

  float i0 = 1.0f / __shfl(lr, hi * 4 + 0);
  float i1 = 1.0f / __shfl(lr, hi * 4 + 1);
  float i2 = 1.0f / __shfl(lr, hi * 4 + 2);
  float i3 = 1.0f / __shfl(lr, hi * 4 + 3);
  size_t rbase = (size_t)b * 2048 + q0 + hi * 4;
#pragma unroll
  for (int df = 0; df < 4; df++) {
    int cc = h * 64 + df * 16 + lo;
    ctx[(rbase + 0) * 1024 + cc] = f2bfbits(O[df][0] * i0);
    ctx[(rbase + 1) * 1024 + cc] = f2bfbits(O[df][1] * i1);
    ctx[(rbase + 2) * 1024 + cc] = f2bfbits(O[df][2] * i2);
    ctx[(rbase + 3) * 1024 + cc] = f2bfbits(O[df][3] * i3);
  }
}

// ---------------------------------------------------------------- launch
extern "C" void kernel_launch(void* const* d_in, const int* in_sizes, int n_in,
                              void* d_out, int out_size, void* d_ws, size_t ws_size,
                              hipStream_t stream) {
  const float* x   = (const float*)d_in[0];
  const float* y   = (const float*)d_in[1];
  const unsigned char* pmask = (const unsigned char*)d_in[2];
  const float* Wq  = (const float*)d_in[3];
  const float* bq  = (const float*)d_in[4];
  const float* Wkv = (const float*)d_in[5];
  const float* bkv = (const float*)d_in[6];
  const float* qnw = (const float*)d_in[7];
  const float* qnb = (const float*)d_in[8];
  const float* knw = (const float*)d_in[9];
  const float* knb = (const float*)d_in[10];
  const float* Wo  = (const float*)d_in[11];
  const float* bo  = (const float*)d_in[12];
  float* out = (float*)d_out;

  const size_t MB = 1024ull * 1024ull;
  char* ws = (char*)d_ws;
  float* maddC         = (float*)ws;                                // 24 KB
  int*   invperm       = (int*)(ws + 24576);                        // 24 KB
  int*   nvalid        = (int*)(ws + 49152);                        //  8 B
  char*  wb            = ws + 131072;
  unsigned short* Wqb  = (unsigned short*)(wb);                     //  2 MiB
  unsigned short* Wkvb = (unsigned short*)(wb + 2 * MB);            //  4 MiB
  unsigned short* Wob  = (unsigned short*)(wb + 6 * MB);            //  2 MiB
  unsigned short* qln  = (unsigned short*)(wb + 8 * MB);            //  8 MiB
  unsigned short* kln  = (unsigned short*)(wb + 16 * MB);           // 12 MiB
  unsigned short* vt   = (unsigned short*)(wb + 28 * MB);           // 12 MiB
  unsigned short* ctxb = (unsigned short*)(wb + 40 * MB);           //  8 MiB
  unsigned short* yb   = (unsigned short*)(wb + 48 * MB);           // 12 MiB
  unsigned short* xb   = (unsigned short*)(wb + 60 * MB);           //  8 MiB
  unsigned short* vrow = (unsigned short*)(wb + 68 * MB);           // 12 MiB
  if (ws_size < 131072 + 80 * MB) return;

  // converts + mask scan/compaction, one launch
  fused_prep<<<dim3(7170), dim3(256), 0, stream>>>(
      x, xb, y, yb, Wq, Wqb, Wkv, Wkvb, Wo, Wob, pmask, maddC, invperm,
      nvalid);

  // q + kv projections (+fused LN; all outputs coalesced/unpermuted)
  gemm_qkv<<<dim3(1024), dim3(256), 0, stream>>>(
      xb, Wqb, bq, qnw, qnb, qln, yb, Wkvb, bkv, knw, knb, kln, vrow);

  // V: gather (compaction) + transpose -> vt[bh][d][slot]
  v_tr<<<dim3(96, 16), dim3(256), 0, stream>>>(vrow, invperm, vt);

  attn_fwd<<<dim3(32, 32), dim3(256), 0, stream>>>(qln, kln, vt, maddC,
                                                   invperm, nvalid, ctxb);

  // out = ctx@Wo^T + bo  (512-thread, 8-wave, 2-phase dbuf)
  gemm_out<<<dim3(8, 32), dim3(512), 0, stream>>>(ctxb, Wob, bo, out, 1024, 1024);
}

// Round 16
// 143.869 us; speedup vs baseline: 1.0212x; 1.0212x over previous
//
#include <hip/hip_runtime.h>
#include <stdint.h>
#include <stddef.h>

typedef __attribute__((ext_vector_type(4))) float  f32x4;
typedef __attribute__((ext_vector_type(8))) short  short8;
typedef __attribute__((ext_vector_type(4))) short  short4v;
typedef __attribute__((ext_vector_type(2))) unsigned int uint2v;

__device__ __forceinline__ unsigned short f2bfbits(float f) {
  unsigned int u = __builtin_bit_cast(unsigned int, f);
  u += 0x7FFFu + ((u >> 16) & 1u);   // RNE
  return (unsigned short)(u >> 16);
}

__device__ __forceinline__ f32x4 mfma16(short8 a, short8 b, f32x4 c) {
  return __builtin_amdgcn_mfma_f32_16x16x32_bf16(a, b, c, 0, 0, 0);
}

__device__ __forceinline__ unsigned int cvtpk(float a, float b) {
  unsigned int r;
  asm volatile("v_cvt_pk_bf16_f32 %0, %1, %2" : "=v"(r) : "v"(a), "v"(b));
  return r;
}

__device__ __forceinline__ void gload16(const void* g, void* l) {
  __builtin_amdgcn_global_load_lds(
      (const __attribute__((address_space(1))) void*)g,
      (__attribute__((address_space(3))) void*)l, 16, 0, 0);
}

// ---------------------------------------------------------------- fused prep
// Blocks [0,7168): f32->bf16 of {x,y,Wq,Wkv,Wo}.
// Blocks 7168+b: per-batch mask scan -> invperm (slot -> original row;
// bijection) + compacted bias maddC[b][slot] = -10 (slot<nvalid) / -1e30.
__device__ __forceinline__ void cvt_block(const float* __restrict__ in,
                                          unsigned short* __restrict__ out,
                                          int blk, int t) {
  size_t i = (size_t)blk * 256 + t;    // in units of 8 elements
  f32x4 a = *(const f32x4*)(in + i * 8);
  f32x4 b = *(const f32x4*)(in + i * 8 + 4);
  short8 o;
  o[0] = (short)f2bfbits(a[0]); o[1] = (short)f2bfbits(a[1]);
  o[2] = (short)f2bfbits(a[2]); o[3] = (short)f2bfbits(a[3]);
  o[4] = (short)f2bfbits(b[0]); o[5] = (short)f2bfbits(b[1]);
  o[6] = (short)f2bfbits(b[2]); o[7] = (short)f2bfbits(b[3]);
  *(short8*)(out + i * 8) = o;
}

__global__ __launch_bounds__(256) void fused_prep(
    const float* __restrict__ x, unsigned short* __restrict__ xb,
    const float* __restrict__ y, unsigned short* __restrict__ yb,
    const float* __restrict__ Wq, unsigned short* __restrict__ Wqb,
    const float* __restrict__ Wkv, unsigned short* __restrict__ Wkvb,
    const float* __restrict__ Wo, unsigned short* __restrict__ Wob,
    const unsigned char* __restrict__ mraw, float* __restrict__ maddC,
    int* __restrict__ invperm, int* __restrict__ nvalid) {
  const int bid = blockIdx.x, t = threadIdx.x;
  if (bid < 2048)       { cvt_block(x,   xb,   bid,        t); return; }
  else if (bid < 5120)  { cvt_block(y,   yb,   bid - 2048, t); return; }
  else if (bid < 5632)  { cvt_block(Wq,  Wqb,  bid - 5120, t); return; }
  else if (bid < 6656)  { cvt_block(Wkv, Wkvb, bid - 5632, t); return; }
  else if (bid < 7168)  { cvt_block(Wo,  Wob,  bid - 6656, t); return; }

  // ---- mask scan block (one per batch) ----
  const int batch = bid - 7168;
  __shared__ int s_na, s_gt, s_m84;
  if (t == 0) { s_na = 0; s_gt = 0; s_m84 = 0; }
  __syncthreads();
  int na = 0, gt = 0, m84 = 0;
  for (int i = t; i < 4096; i += 256) {
    unsigned char v = mraw[i];
    if (v) {
      if (i & 3) na++;
      if ((i & 7) == 4) m84++;
      if (v > 1) gt++;
    }
  }
  atomicAdd(&s_na, na); atomicAdd(&s_gt, gt); atomicAdd(&s_m84, m84);
  __syncthreads();
  int layout;                        // 0=bool8 1=int32 2=float32 3=int64
  if (s_na == 0) layout = s_m84 ? 1 : 3;
  else           layout = s_gt ? 2 : 0;

  const int base = batch * 3072;
  int myv[12];
  int cnt = 0;
#pragma unroll
  for (int k = 0; k < 12; k++) {
    int j = t * 12 + k;
    int gj = base + j;
    bool mv;
    if (layout == 0)      mv = mraw[gj] != 0;
    else if (layout == 1) mv = ((const int*)mraw)[gj] != 0;
    else if (layout == 2) mv = ((const float*)mraw)[gj] > 0.5f;
    else                  mv = ((const long long*)mraw)[gj] != 0;
    myv[k] = mv ? 1 : 0;
    cnt += myv[k];
  }
  const int lane = t & 63, wv = t >> 6;
  int inc = cnt;
#pragma unroll
  for (int d = 1; d < 64; d <<= 1) {
    int n = __shfl_up(inc, d);
    if (lane >= d) inc += n;
  }
  __shared__ int wsum[4];
  if (lane == 63) wsum[wv] = inc;
  __syncthreads();
  int woff = 0;
#pragma unroll
  for (int i2 = 0; i2 < 4; i2++) if (i2 < wv) woff += wsum[i2];
  const int total = wsum[0] + wsum[1] + wsum[2] + wsum[3];
  int vp = woff + inc - cnt;         // #valid before my first element
  if (t == 0) nvalid[batch] = total;
#pragma unroll
  for (int k = 0; k < 12; k++) {
    int j = t * 12 + k;
    int slot = myv[k] ? vp : (total + (j - vp));
    invperm[base + slot] = j;
    vp += myv[k];
  }
  for (int jj = t; jj < 3072; jj += 256)
    maddC[base + jj] = (jj < total) ? -10.0f : -1e30f;
}

// ---------------------------------------------------------------- qkv GEMM
// Merged q + kv projection, flat 1024-block launch, XCD-balanced swizzle.
// Single-buffer 2-barrier loop (r12 structure; explicit dbuf was null).
// __launch_bounds__(256,3): force regs <=170 -> 3 waves/SIMD (was 184 regs
// = 2 waves/SIMD, the occupancy cap the counters showed for 3 rounds).
__global__ __launch_bounds__(256, 3) void gemm_qkv(
    const unsigned short* __restrict__ xb, const unsigned short* __restrict__ Wqb,
    const float* __restrict__ bq, const float* __restrict__ qnw,
    const float* __restrict__ qnb, unsigned short* __restrict__ qln,
    const unsigned short* __restrict__ yb, const unsigned short* __restrict__ Wkvb,
    const float* __restrict__ bkv, const float* __restrict__ knw,
    const float* __restrict__ knb, unsigned short* __restrict__ kln,
    unsigned short* __restrict__ vrow) {
  __shared__ unsigned short As[128 * 64];
  __shared__ unsigned short Bs[128 * 64];
  const int t = threadIdx.x, l = t & 63, w = t >> 6;
  const int lo = l & 15, hi = l >> 4;
  const int wr = w >> 1, wc = w & 1;
  const int flat = blockIdx.x;
  int vb;
  if (flat < 256) vb = (flat & 7) * 32 + (flat >> 3);
  else { int f2 = flat - 256; vb = 256 + (f2 & 7) * 96 + (f2 >> 3); }
  const int isq = vb < 256;
  const int bn = isq ? (vb & 7) : ((vb - 256) & 15);
  const int bm = isq ? (vb >> 3) : ((vb - 256) >> 4);
  const unsigned short* A = isq ? xb : yb;
  const unsigned short* B = isq ? Wqb : Wkvb;
  const float* bias = isq ? bq : bkv;
  const float* lnw = isq ? qnw : knw;
  const float* lnb = isq ? qnb : knb;
  unsigned short* bfout = isq ? qln : kln;
  const float lnscale = isq ? 0.125f * 1.44269504f : 1.0f;
  const int rpb = isq ? 2048 : 3072;
  const int K = 1024;

  const int sr = l >> 3;
  const int sc = ((l & 7) ^ sr) << 3;
  const unsigned short* Ab = A + (size_t)bm * 128 * K + (size_t)sr * K + sc;
  const unsigned short* Bb = B + (size_t)bn * 128 * K + (size_t)sr * K + sc;

  f32x4 acc[4][4] = {};

  for (int kt = 0; kt < K; kt += 64) {
    __syncthreads();
#pragma unroll
    for (int p = 0; p < 4; ++p) {
      int c = w * 4 + p;
      gload16(Ab + (size_t)c * 8 * K + kt, &As[c * 512]);
      gload16(Bb + (size_t)c * 8 * K + kt, &Bs[c * 512]);
    }
    __syncthreads();
#pragma unroll
    for (int kk = 0; kk < 2; ++kk) {
      short8 af[4], bf[4];
#pragma unroll
      for (int i = 0; i < 4; ++i) {
        int slot = (((kk * 4 + hi) ^ (lo & 7)) << 3);
        af[i] = *(const short8*)&As[(wr * 64 + i * 16 + lo) * 64 + slot];
        bf[i] = *(const short8*)&Bs[(wc * 64 + i * 16 + lo) * 64 + slot];
      }
#pragma unroll
      for (int i = 0; i < 4; ++i)
#pragma unroll
        for (int j = 0; j < 4; ++j)
          acc[i][j] = mfma16(af[i], bf[j], acc[i][j]);
    }
  }

  float bv[4];
#pragma unroll
  for (int j = 0; j < 4; ++j) bv[j] = bias[bn * 128 + wc * 64 + j * 16 + lo];
#pragma unroll
  for (int i = 0; i < 4; ++i)
#pragma unroll
    for (int j = 0; j < 4; ++j)
#pragma unroll
      for (int r = 0; r < 4; ++r) acc[i][j][r] += bv[j];

  if (!isq && bn >= 8) {
    // V half: coalesced bf16 store, original row order (j = kv row)
#pragma unroll
    for (int j = 0; j < 4; ++j) {
      int col = bn * 128 + wc * 64 + j * 16 + lo;
      int vcol = col - 1024;
#pragma unroll
      for (int i = 0; i < 4; ++i) {
        int row = bm * 128 + wr * 64 + i * 16 + hi * 4;
#pragma unroll
        for (int r = 0; r < 4; ++r)
          vrow[(size_t)(row + r) * 1024 + vcol] = f2bfbits(acc[i][j][r]);
      }
    }
  } else {
    // fused per-head LayerNorm -> bf16 head-major [b*16+h][rpb][64]
    float gwv[4], gbv[4];
#pragma unroll
    for (int j = 0; j < 4; ++j) {
      gwv[j] = lnw[j * 16 + lo];
      gbv[j] = lnb[j * 16 + lo];
    }
    const int hcol = (bn * 128 + wc * 64) >> 6;
#pragma unroll
    for (int i = 0; i < 4; ++i) {
#pragma unroll
      for (int r = 0; r < 4; ++r) {
        float s1 = (acc[i][0][r] + acc[i][1][r]) + (acc[i][2][r] + acc[i][3][r]);
        float s2 = (acc[i][0][r] * acc[i][0][r] + acc[i][1][r] * acc[i][1][r]) +
                   (acc[i][2][r] * acc[i][2][r] + acc[i][3][r] * acc[i][3][r]);
#pragma unroll
        for (int m = 1; m < 16; m <<= 1) {
          s1 += __shfl_xor(s1, m);
          s2 += __shfl_xor(s2, m);
        }
        float mu = s1 * 0.015625f;
        float var = fmaxf(s2 * 0.015625f - mu * mu, 0.0f);
        float rq = rsqrtf(var + 1e-6f);
        int row = bm * 128 + wr * 64 + i * 16 + hi * 4 + r;
        int bb = row >= rpb;
        int rr = row - bb * rpb;
        size_t base = ((size_t)(bb * 16 + hcol) * rpb + rr) * 64;
#pragma unroll
        for (int j = 0; j < 4; ++j)
          bfout[base + j * 16 + lo] =
              f2bfbits(((acc[i][j][r] - mu) * rq * gwv[j] + gbv[j]) * lnscale);
      }
    }
  }
}

// ---------------------------------------------------------------- V gather+T
// vt[(b*16+h)*64 + d][slot] = vrow[b*3072 + invperm[slot]][h*64 + d].
__global__ __launch_bounds__(256) void v_tr(
    const unsigned short* __restrict__ vrow, const int* __restrict__ invperm,
    unsigned short* __restrict__ vt) {
  __shared__ unsigned short tile[64][65];
  const int jt = blockIdx.x, h = blockIdx.y;   // jt 0..95 (48 per batch)
  const int b = jt / 48, j0 = (jt % 48) * 64;
  const int t = threadIdx.x;
  const int r = t >> 2, c0 = (t & 3) << 4;
  const int sj = invperm[b * 3072 + j0 + r];
  const unsigned short* src = vrow + ((size_t)b * 3072 + sj) * 1024 + h * 64 + c0;
  *(short8*)&tile[r][c0]     = *(const short8*)src;
  *(short8*)&tile[r][c0 + 8] = *(const short8*)(src + 8);
  __syncthreads();
  const int d = t >> 2, jc = (t & 3) << 4;
  unsigned short* dst = vt + ((size_t)((b * 16 + h) * 64 + d)) * 3072 + j0 + jc;
  short8 o0, o1;
#pragma unroll
  for (int i = 0; i < 8; i++) o0[i] = tile[jc + i][d];
#pragma unroll
  for (int i = 0; i < 8; i++) o1[i] = tile[jc + 8 + i][d];
  *(short8*)dst = o0;
  *(short8*)(dst + 8) = o1;
}

// ---------------------------------------------------------------- out GEMM
// out = ctx@Wo^T + bo. 512 threads, 8 waves (4M x 2N), single-buffer.
// __launch_bounds__(512,4): cap regs at 128 -> 2 blocks/CU (4 waves/SIMD).
__global__ __launch_bounds__(512, 4) void gemm_out(
    const unsigned short* __restrict__ A, const unsigned short* __restrict__ B,
    const float* __restrict__ bias, float* __restrict__ C, int N, int K) {
  __shared__ unsigned short As[128 * 64];
  __shared__ unsigned short Bs[128 * 64];
  const int t = threadIdx.x, l = t & 63, w = t >> 6;
  const int lo = l & 15, hi = l >> 4;
  const int wr = w >> 1, wc = w & 1;          // 4M x 2N
  const int bn = blockIdx.x, bm = blockIdx.y;

  const int sr = l >> 3;
  const int sc = ((l & 7) ^ sr) << 3;
  const unsigned short* Ab = A + (size_t)bm * 128 * K + (size_t)sr * K + sc;
  const unsigned short* Bb = B + (size_t)bn * 128 * K + (size_t)sr * K + sc;

  f32x4 acc[2][4] = {};

  for (int kt = 0; kt < K; kt += 64) {
    __syncthreads();
#pragma unroll
    for (int p = 0; p < 2; ++p) {
      int c = p * 8 + w;
      gload16(Ab + (size_t)c * 8 * K + kt, &As[c * 512]);
      gload16(Bb + (size_t)c * 8 * K + kt, &Bs[c * 512]);
    }
    __syncthreads();
#pragma unroll
    for (int kk = 0; kk < 2; ++kk) {
      short8 af[2], bf[4];
#pragma unroll
      for (int i = 0; i < 2; ++i) {
        int slot = (((kk * 4 + hi) ^ (lo & 7)) << 3);
        af[i] = *(const short8*)&As[(wr * 32 + i * 16 + lo) * 64 + slot];
      }
#pragma unroll
      for (int j = 0; j < 4; ++j) {
        int slot = (((kk * 4 + hi) ^ (lo & 7)) << 3);
        bf[j] = *(const short8*)&Bs[(wc * 64 + j * 16 + lo) * 64 + slot];
      }
#pragma unroll
      for (int i = 0; i < 2; ++i)
#pragma unroll
        for (int j = 0; j < 4; ++j)
          acc[i][j] = mfma16(af[i], bf[j], acc[i][j]);
    }
  }

#pragma unroll
  for (int j = 0; j < 4; ++j) {
    int col = bn * 128 + wc * 64 + j * 16 + lo;
    float bv = bias[col];
#pragma unroll
    for (int i = 0; i < 2; ++i) {
      int row = bm * 128 + wr * 32 + i * 16 + hi * 4;
#pragma unroll
      for (int r = 0; r < 4; ++r)
        C[(size_t)(row + r) * N + col] = acc[i][j][r] + bv;
    }
  }
}

// ---------------------------------------------------------------- attention
// Round-12 structure (proven): KVBLK=64, 40 KB LDS, T15 2-deep pipeline,
// KV compacted via invperm gather at K staging, 128B-row XOR swizzle.
// Fully-valid tiles use CONSTANT -10 as the QK C-init.
__global__ __launch_bounds__(256, 4) void attn_fwd(
    const unsigned short* __restrict__ Q, const unsigned short* __restrict__ KnU,
    const unsigned short* __restrict__ Vt, const float* __restrict__ maskAdd,
    const int* __restrict__ invperm, const int* __restrict__ nva,
    unsigned short* __restrict__ ctx) {
  int flat = blockIdx.y * 32 + blockIdx.x;
  int f = (flat & 7) * 128 + (flat >> 3);       // XCD i owns bh in [4i,4i+4)
  const int bh = f >> 5, qb = f & 31;
  const int b = bh >> 4, h = bh & 15;
  const int t = threadIdx.x, l = t & 63, w = t >> 6;
  const int lo = l & 15, hi = l >> 4;
  const int q0 = qb * 64 + w * 16;

  const int nv = nva[b];
  const int kend = (nv + 63) & ~63;             // >= 64 (mask[:,0]=True)

  __shared__ unsigned short lds[20480];         // 40 KB exactly
  unsigned short* Ks = lds;                     // [2][64][64]
  unsigned short* Vs = lds + 8192;              // [2][64][64]
  unsigned short* P  = lds + 16384 + w * 1024;  // [16][64] swizzled

  const unsigned short* Qh = Q + ((size_t)bh * 2048 + q0) * 64;
  const unsigned short* KbU = KnU + (size_t)bh * 3072 * 64;
  const unsigned short* Vb = Vt + (size_t)bh * 64 * 3072;
  const float* mb = maskAdd + b * 3072;
  const int ibase = b * 3072;

  const int srow = w * 8 + (l >> 3);            // in [0,32)
  const int swz8 = ((l & 7) ^ ((l >> 3) & 7)) << 3;
  const unsigned short* vS = Vb + (size_t)srow * 3072 + swz8;
  const int dstoff = w * 512;

  short8 qf[2];
#pragma unroll
  for (int g = 0; g < 2; g++)
    qf[g] = *(const short8*)(Qh + (size_t)lo * 64 + g * 32 + hi * 8);

  f32x4 O[4] = {};
  f32x4 lacc = {};
  const int myswz = (lo & 7) << 3;

  short8 paR[2] = {};
  short8 vfR[4][2] = {};

  // rows for tile 0
  int rs0 = invperm[ibase + srow];
  int rs1 = invperm[ibase + 32 + srow];
  gload16(KbU + (size_t)rs0 * 64 + swz8, Ks + dstoff);
  gload16(KbU + (size_t)rs1 * 64 + swz8, Ks + 2048 + dstoff);
  gload16(vS, Vs + dstoff);
  gload16(vS + 98304, Vs + 2048 + dstoff);
  {
    int kt1 = (64 < kend) ? 64 : 0;
    rs0 = invperm[ibase + kt1 + srow];
    rs1 = invperm[ibase + kt1 + 32 + srow];
  }
  __syncthreads();

  for (int kt = 0; kt < kend; kt += 64) {
    const int cur = (kt >> 6) & 1;
    const int nxt = cur ^ 1;
    const int ktn = (kt + 64 < kend) ? kt + 64 : 0;
    gload16(KbU + (size_t)rs0 * 64 + swz8, Ks + nxt * 4096 + dstoff);
    gload16(KbU + (size_t)rs1 * 64 + swz8, Ks + nxt * 4096 + 2048 + dstoff);
    gload16(vS + ktn, Vs + nxt * 4096 + dstoff);
    gload16(vS + ktn + 98304, Vs + nxt * 4096 + 2048 + dstoff);
    {
      int ktn2 = (kt + 128 < kend) ? kt + 128 : 0;
      rs0 = invperm[ibase + ktn2 + srow];
      rs1 = invperm[ibase + ktn2 + 32 + srow];
    }

    const unsigned short* Kc = Ks + cur * 4096;
    const unsigned short* Vc = Vs + cur * 4096;

    // QK^T(t) with mask bias as C-init; constant -10 for fully-valid tiles
    f32x4 s[4];
    if (kt + 64 <= nv) {
#pragma unroll
      for (int nf = 0; nf < 4; nf++)
        s[nf] = f32x4{-10.0f, -10.0f, -10.0f, -10.0f};
    } else {
#pragma unroll
      for (int nf = 0; nf < 4; nf++)
        s[nf] = *(const f32x4*)(mb + kt + nf * 16 + hi * 4);
    }
    __builtin_amdgcn_s_setprio(1);
#pragma unroll
    for (int nf = 0; nf < 4; nf++) {
      const int row = nf * 16 + lo;
      short8 k0 = *(const short8*)&Kc[row * 64 + ((hi * 8) ^ myswz)];
      short8 k1 = *(const short8*)&Kc[row * 64 + ((32 + hi * 8) ^ myswz)];
      s[nf] = mfma16(k0, qf[0], s[nf]);
      s[nf] = mfma16(k1, qf[1], s[nf]);
    }

    // PV(t-1): register-only MFMA cluster
#pragma unroll
    for (int df = 0; df < 4; df++)
#pragma unroll
      for (int ks = 0; ks < 2; ks++)
        O[df] = mfma16(paR[ks], vfR[df][ks], O[df]);
    __builtin_amdgcn_s_setprio(0);

    // P = exp2(S + bias)
#pragma unroll
    for (int nf = 0; nf < 4; nf++)
#pragma unroll
      for (int r = 0; r < 4; r++)
        s[nf][r] = __builtin_amdgcn_exp2f(s[nf][r]);
    lacc += (s[0] + s[1]) + (s[2] + s[3]);

    // P(t) -> LDS, preload pa(t)/vf(t) pipeline regs
#pragma unroll
    for (int nf = 0; nf < 4; nf++) {
      uint2v u;
      u.x = cvtpk(s[nf][0], s[nf][1]);
      u.y = cvtpk(s[nf][2], s[nf][3]);
      *(uint2v*)&P[lo * 64 + ((nf * 16 + hi * 4) ^ myswz)] = u;
    }
#pragma unroll
    for (int ks = 0; ks < 2; ks++)
      paR[ks] = *(const short8*)&P[lo * 64 + ((ks * 32 + hi * 8) ^ myswz)];
#pragma unroll
    for (int df = 0; df < 4; df++) {
      const int row = df * 16 + lo;
#pragma unroll
      for (int ks = 0; ks < 2; ks++)
        vfR[df][ks] = *(const short8*)&Vc[row * 64 + ((ks * 32 + hi * 8) ^ myswz)];
    }

    __syncthreads();   // drains vmcnt+lgkm: paR/vfR live; buffers safe
  }

  // epilogue: PV of the last tile
  __builtin_amdgcn_s_setprio(1);
#pragma unroll
  for (int df = 0; df < 4; df++)
#pragma unroll
    for (int ks = 0; ks < 2; ks++)
      O[df] = mfma16(paR[ks], vfR[df][ks], O[df]);
  __builtin_amdgcn_s_setprio(0);

  float lr = (lacc[0] + lacc[1]) + (lacc[2] + lacc[3]);
  lr += __shfl_xor(lr, 16);
  lr += __shfl_xor(lr, 32);

  float i0 = 1.0f / __shfl(lr, hi * 4 + 0);
  float i1 = 1.0f / __shfl(lr, hi * 4 + 1);
  float i2 = 1.0f / __shfl(lr, hi * 4 + 2);
  float i3 = 1.0f / __shfl(lr, hi * 4 + 3);
  size_t rbase = (size_t)b * 2048 + q0 + hi * 4;
#pragma unroll
  for (int df = 0; df < 4; df++) {
    int cc = h * 64 + df * 16 + lo;
    ctx[(rbase + 0) * 1024 + cc] = f2bfbits(O[df][0] * i0);
    ctx[(rbase + 1) * 1024 + cc] = f2bfbits(O[df][1] * i1);
    ctx[(rbase + 2) * 1024 + cc] = f2bfbits(O[df][2] * i2);
    ctx[(rbase + 3) * 1024 + cc] = f2bfbits(O[df][3] * i3);
  }
}

// ---------------------------------------------------------------- launch
extern "C" void kernel_launch(void* const* d_in, const int* in_sizes, int n_in,
                              void* d_out, int out_size, void* d_ws, size_t ws_size,
                              hipStream_t stream) {
  const float* x   = (const float*)d_in[0];
  const float* y   = (const float*)d_in[1];
  const unsigned char* pmask = (const unsigned char*)d_in[2];
  const float* Wq  = (const float*)d_in[3];
  const float* bq  = (const float*)d_in[4];
  const float* Wkv = (const float*)d_in[5];
  const float* bkv = (const float*)d_in[6];
  const float* qnw = (const float*)d_in[7];
  const float* qnb = (const float*)d_in[8];
  const float* knw = (const float*)d_in[9];
  const float* knb = (const float*)d_in[10];
  const float* Wo  = (const float*)d_in[11];
  const float* bo  = (const float*)d_in[12];
  float* out = (float*)d_out;

  const size_t MB = 1024ull * 1024ull;
  char* ws = (char*)d_ws;
  float* maddC         = (float*)ws;                                // 24 KB
  int*   invperm       = (int*)(ws + 24576);                        // 24 KB
  int*   nvalid        = (int*)(ws + 49152);                        //  8 B
  char*  wb            = ws + 131072;
  unsigned short* Wqb  = (unsigned short*)(wb);                     //  2 MiB
  unsigned short* Wkvb = (unsigned short*)(wb + 2 * MB);            //  4 MiB
  unsigned short* Wob  = (unsigned short*)(wb + 6 * MB);            //  2 MiB
  unsigned short* qln  = (unsigned short*)(wb + 8 * MB);            //  8 MiB
  unsigned short* kln  = (unsigned short*)(wb + 16 * MB);           // 12 MiB
  unsigned short* vt   = (unsigned short*)(wb + 28 * MB);           // 12 MiB
  unsigned short* ctxb = (unsigned short*)(wb + 40 * MB);           //  8 MiB
  unsigned short* yb   = (unsigned short*)(wb + 48 * MB);           // 12 MiB
  unsigned short* xb   = (unsigned short*)(wb + 60 * MB);           //  8 MiB
  unsigned short* vrow = (unsigned short*)(wb + 68 * MB);           // 12 MiB
  if (ws_size < 131072 + 80 * MB) return;

  // converts + mask scan/compaction, one launch
  fused_prep<<<dim3(7170), dim3(256), 0, stream>>>(
      x, xb, y, yb, Wq, Wqb, Wkv, Wkvb, Wo, Wob, pmask, maddC, invperm,
      nvalid);

  // q + kv projections (+fused LN; all outputs coalesced/unpermuted)
  gemm_qkv<<<dim3(1024), dim3(256), 0, stream>>>(
      xb, Wqb, bq, qnw, qnb, qln, yb, Wkvb, bkv, knw, knb, kln, vrow);

  // V: gather (compaction) + transpose -> vt[bh][d][slot]
  v_tr<<<dim3(96, 16), dim3(256), 0, stream>>>(vrow, invperm, vt);

  attn_fwd<<<dim3(32, 32), dim3(256), 0, stream>>>(qln, kln, vt, maddC,
                                                   invperm, nvalid, ctxb);

  // out = ctx@Wo^T + bo  (512-thread, 8-wave)
  gemm_out<<<dim3(8, 32), dim3(512), 0, stream>>>(ctxb, Wob, bo, out, 1024, 1024);
}